// Round 1
// baseline (705.834 us; speedup 1.0000x reference)
//
#include <hip/hip_runtime.h>
#include <math.h>

#define SP_IN   3136   // 56*56
#define HID     196
#define NPLANES 256
#define NB      64
#define NREM    1568   // removed per row
#define P4      784    // SP_IN/4

// ---------------- K0: transpose W2 [3136][196] -> W2T [196][3136] ----------
__global__ __launch_bounds__(256) void k0_transpose(const float* __restrict__ W2,
                                                    float* __restrict__ W2T) {
  __shared__ float t[32][33];
  const int tx = threadIdx.x, ty = threadIdx.y;          // 32 x 8
  const int r0 = blockIdx.y * 32, c0 = blockIdx.x * 32;  // r: o-dim (3136), c: h-dim (196)
  for (int i = ty; i < 32; i += 8) {
    int c = c0 + tx;
    t[i][tx] = (c < HID) ? W2[(r0 + i) * HID + c] : 0.f;
  }
  __syncthreads();
  for (int i = ty; i < 32; i += 8) {
    int h = c0 + i;
    if (h < HID) W2T[h * SP_IN + (r0 + tx)] = t[tx][i];
  }
}

// ---------------- K1: channel-mean pool (fp64 accumulate) ------------------
__global__ __launch_bounds__(256) void k1_pool(const float* __restrict__ x,
                                               double* __restrict__ y) {
  const int idx = blockIdx.x * 256 + threadIdx.x;  // 0 .. 64*784-1
  const int b = idx / P4, p4 = idx - b * P4;
  const float4* xp = (const float4*)x + (size_t)b * (NPLANES * P4) + p4;
  double a0 = 0, a1 = 0, a2 = 0, a3 = 0;
#pragma unroll 8
  for (int c = 0; c < NPLANES; ++c) {
    float4 v = xp[(size_t)c * P4];
    a0 += v.x; a1 += v.y; a2 += v.z; a3 += v.w;
  }
  const double s = 1.0 / NPLANES;
  double2* yp = (double2*)(y + (size_t)b * SP_IN + p4 * 4);
  yp[0] = make_double2(a0 * s, a1 * s);
  yp[1] = make_double2(a2 * s, a3 * s);
}

__device__ __forceinline__ unsigned int fkey(float f) {
  unsigned int u = __float_as_uint(f);
  return (u & 0x80000000u) ? ~u : (u | 0x80000000u);  // monotone total order
}

// ---------------- K2: per-row MLP + exact top-k mask -----------------------
__global__ __launch_bounds__(256, 1) void k2_mlp(const double* __restrict__ y,
                                                 const float* __restrict__ W1,
                                                 const float* __restrict__ W2T,
                                                 float* __restrict__ y2m) {
  __shared__ double y_s[SP_IN];     // 25 KB
  __shared__ double pre_s[SP_IN];   // 25 KB  pre-sigmoid values
  __shared__ double h_s[HID];
  __shared__ unsigned int hist[256];
  __shared__ unsigned char rm_s[SP_IN];
  __shared__ int eqidx[64];
  __shared__ int eqcnt;
  __shared__ unsigned int prefix_s;
  __shared__ int rank_s;

  const int b = blockIdx.x;
  const int t = threadIdx.x;
  const int lane = t & 63, wv = t >> 6;

  for (int i = t; i < SP_IN; i += 256) y_s[i] = y[(size_t)b * SP_IN + i];
  if (t == 0) { eqcnt = 0; prefix_s = 0; rank_s = NREM; }
  __syncthreads();

  // GEMM1: h[o] = relu(sum_k W1[o][k] * y[k]); wave wv owns outputs [wv*49, wv*49+49)
  {
    double p[49];
#pragma unroll
    for (int o = 0; o < 49; ++o) p[o] = 0.0;
    const float* wbase = W1 + (size_t)(wv * 49) * SP_IN + lane;
    for (int jb = 0; jb < 7; ++jb) {  // k = lane + 64*j, j = 7*jb + jj
      double yv[7];
#pragma unroll
      for (int jj = 0; jj < 7; ++jj) yv[jj] = y_s[lane + 64 * (jb * 7 + jj)];
      const float* wp = wbase + 64 * (jb * 7);
#pragma unroll
      for (int o = 0; o < 49; ++o) {
        const float* wpo = wp + o * SP_IN;
#pragma unroll
        for (int jj = 0; jj < 7; ++jj) p[o] += (double)wpo[64 * jj] * yv[jj];
      }
    }
#pragma unroll
    for (int o = 0; o < 49; ++o) {
      double v = p[o];
#pragma unroll
      for (int d = 32; d; d >>= 1) v += __shfl_xor(v, d, 64);
      if (lane == 0) h_s[wv * 49 + o] = v > 0.0 ? v : 0.0;
    }
  }
  __syncthreads();

  // GEMM2: pre[o] = sum_h W2T[h][o] * h_s[h]   (coalesced float4 over o)
  for (int o4 = t; o4 < P4; o4 += 256) {
    double a0 = 0, a1 = 0, a2 = 0, a3 = 0;
    const float4* wp = (const float4*)W2T + o4;
#pragma unroll 4
    for (int hh = 0; hh < HID; ++hh) {
      float4 w = wp[(size_t)hh * P4];
      double hv = h_s[hh];
      a0 += w.x * hv; a1 += w.y * hv; a2 += w.z * hv; a3 += w.w * hv;
    }
    pre_s[o4 * 4 + 0] = a0;
    pre_s[o4 * 4 + 1] = a1;
    pre_s[o4 * 4 + 2] = a2;
    pre_s[o4 * 4 + 3] = a3;
  }
  __syncthreads();

  // Radix select (MSB-first, 4x8-bit) for the NREM-th smallest float key.
  for (int shift = 24; shift >= 0; shift -= 8) {
    hist[t] = 0;
    __syncthreads();
    const unsigned int pfx = prefix_s;
    const unsigned int pmask = (shift == 24) ? 0u : (0xFFFFFFFFu << (shift + 8));
    const int r = rank_s;
    for (int i = t; i < SP_IN; i += 256) {
      unsigned int k = fkey((float)pre_s[i]);
      if ((k & pmask) == pfx) atomicAdd(&hist[(k >> shift) & 0xFFu], 1u);
    }
    __syncthreads();
    if (wv == 0) {  // wave-parallel scan of the 256 bins
      unsigned int h0 = hist[lane * 4], h1 = hist[lane * 4 + 1],
                   h2 = hist[lane * 4 + 2], h3 = hist[lane * 4 + 3];
      unsigned int s = h0 + h1 + h2 + h3;
      unsigned int c = s;
#pragma unroll
      for (int d = 1; d < 64; d <<= 1) {
        unsigned int vv = __shfl_up(c, d, 64);
        if (lane >= d) c += vv;
      }
      unsigned int excl = c - s;
      if (excl < (unsigned)r && c >= (unsigned)r) {  // exactly one lane
        unsigned int cum = excl;
        int bsel = lane * 4;
        if (cum + h0 < (unsigned)r) { cum += h0; ++bsel;
          if (cum + h1 < (unsigned)r) { cum += h1; ++bsel;
            if (cum + h2 < (unsigned)r) { cum += h2; ++bsel; } } }
        rank_s = r - (int)cum;
        prefix_s = pfx | ((unsigned)bsel << shift);
      }
    }
    __syncthreads();
  }
  const unsigned int ustar = prefix_s;  // key of the boundary element
  const int need_eq = rank_s;           // how many key==ustar elems to remove

  // Base flags + gather the (tiny) equal-key class
  for (int i = t; i < SP_IN; i += 256) {
    unsigned int k = fkey((float)pre_s[i]);
    rm_s[i] = (k < ustar) ? 1 : 0;
    if (k == ustar) { int p = atomicAdd(&eqcnt, 1); if (p < 64) eqidx[p] = i; }
  }
  __syncthreads();
  if (t == 0) {  // remove need_eq smallest by (fp64 value, index) — stable-argsort semantics
    int m = eqcnt < 64 ? eqcnt : 64;
    int ne = need_eq < m ? need_eq : m;
    unsigned long long used = 0ull;
    for (int cnt = 0; cnt < ne; ++cnt) {
      int best = -1;
      for (int j = 0; j < m; ++j) {
        if (used & (1ull << j)) continue;
        if (best < 0) { best = j; continue; }
        int ib = eqidx[best], ij = eqidx[j];
        double vb = pre_s[ib], vj = pre_s[ij];
        if (vj < vb || (vj == vb && ij < ib)) best = j;
      }
      used |= (1ull << best);
      rm_s[eqidx[best]] = 1;
    }
  }
  __syncthreads();

  for (int i = t; i < SP_IN; i += 256) {
    double sg = 1.0 / (1.0 + exp(-pre_s[i]));
    y2m[(size_t)b * SP_IN + i] = rm_s[i] ? 0.f : (float)sg;
  }
}

// ---------------- K3: broadcast masked row over 256 planes -----------------
__global__ __launch_bounds__(256) void k3_bcast(const float* __restrict__ y2m,
                                                float* __restrict__ out) {
  const int idx = blockIdx.x * 256 + threadIdx.x;  // 64 b * 64 cgroups * 784 p4
  const int p4 = idx % P4;
  const int rest = idx / P4;
  const int cg = rest & 63;
  const int b = rest >> 6;
  float4 v = ((const float4*)y2m)[b * P4 + p4];
  float4* op = (float4*)out + (size_t)b * (NPLANES * P4) + (size_t)(cg * 4) * P4 + p4;
  op[0] = v;
  op[P4] = v;
  op[2 * P4] = v;
  op[3 * P4] = v;
}

extern "C" void kernel_launch(void* const* d_in, const int* in_sizes, int n_in,
                              void* d_out, int out_size, void* d_ws, size_t ws_size,
                              hipStream_t stream) {
  (void)in_sizes; (void)n_in; (void)out_size; (void)ws_size;
  const float* x  = (const float*)d_in[0];
  const float* W1 = (const float*)d_in[1];
  const float* W2 = (const float*)d_in[2];
  float* out = (float*)d_out;

  char* ws = (char*)d_ws;
  double* y  = (double*)ws;                                            // 1,605,632 B
  float* W2T = (float*)(ws + (size_t)NB * SP_IN * 8);                  // 2,458,624 B
  float* y2m = (float*)(ws + (size_t)NB * SP_IN * 8 + (size_t)HID * SP_IN * 4);  // 802,816 B
  // total ws use ≈ 4.87 MB

  k0_transpose<<<dim3(7, 98), dim3(32, 8), 0, stream>>>(W2, W2T);
  k1_pool<<<dim3(196), dim3(256), 0, stream>>>(x, y);
  k2_mlp<<<dim3(NB), dim3(256), 0, stream>>>(y, W1, W2T, y2m);
  k3_bcast<<<dim3(12544), dim3(256), 0, stream>>>(y2m, out);
}

// Round 2
// 412.920 us; speedup vs baseline: 1.7094x; 1.7094x over previous
//
#include <hip/hip_runtime.h>
#include <math.h>

#define SP_IN   3136   // 56*56
#define HID     196
#define NPLANES 256
#define NB      64
#define NREM    1568   // removed per row
#define P4      784    // SP_IN/4
#define BROW    ((size_t)NB * SP_IN)   // 200704 elements per channel-chunk partial

// ---------------- K0: transpose W2 [3136][196] -> W2T [196][3136] ----------
__global__ __launch_bounds__(256) void k0_transpose(const float* __restrict__ W2,
                                                    float* __restrict__ W2T) {
  __shared__ float t[32][33];
  const int tx = threadIdx.x, ty = threadIdx.y;          // 32 x 8
  const int r0 = blockIdx.y * 32, c0 = blockIdx.x * 32;  // r: o-dim (3136), c: h-dim (196)
  for (int i = ty; i < 32; i += 8) {
    int c = c0 + tx;
    t[i][tx] = (c < HID) ? W2[(r0 + i) * HID + c] : 0.f;
  }
  __syncthreads();
  for (int i = ty; i < 32; i += 8) {
    int h = c0 + i;
    if (h < HID) W2T[h * SP_IN + (r0 + tx)] = t[tx][i];
  }
}

// ---------------- K1: channel-mean pool, 4-way channel split ---------------
// yp[cc][b][3136] fp64 partial sums (unscaled); combined in k2a.
__global__ __launch_bounds__(256) void k1_pool(const float* __restrict__ x,
                                               double* __restrict__ yp) {
  const int gid = blockIdx.x * 256 + threadIdx.x;   // 784 blocks * 256 = 4*64*784
  const int cc = gid / (NB * P4);
  const int r  = gid - cc * (NB * P4);
  const int b  = r / P4, p4 = r - b * P4;
  const float4* xp = (const float4*)x + (size_t)b * (NPLANES * P4)
                   + (size_t)(cc * 64) * P4 + p4;
  double a0 = 0, a1 = 0, a2 = 0, a3 = 0;
#pragma unroll 8
  for (int c = 0; c < 64; ++c) {
    float4 v = xp[(size_t)c * P4];
    a0 += v.x; a1 += v.y; a2 += v.z; a3 += v.w;
  }
  double2* op = (double2*)(yp + (size_t)cc * BROW + (size_t)b * SP_IN + p4 * 4);
  op[0] = make_double2(a0, a1);
  op[1] = make_double2(a2, a3);
}

// ---------------- K2a: GEMM1  h = relu(W1 . y) -----------------------------
// grid (7, 64): blockIdx.x = o-chunk (28 outputs), blockIdx.y = b
__global__ __launch_bounds__(256) void k2a_gemm1(const double* __restrict__ yp,
                                                 const float* __restrict__ W1,
                                                 double* __restrict__ h) {
  __shared__ double y_s[SP_IN];  // 25 KB
  const int b = blockIdx.y, och = blockIdx.x;
  const int t = threadIdx.x, lane = t & 63, wv = t >> 6;

  for (int i = t; i < SP_IN; i += 256) {
    size_t base = (size_t)b * SP_IN + i;
    y_s[i] = (yp[base] + yp[base + BROW] + yp[base + 2 * BROW] + yp[base + 3 * BROW])
             * (1.0 / NPLANES);
  }
  __syncthreads();

  const int o0 = och * 28 + wv * 7;   // this wave's 7 outputs
  double p[7];
#pragma unroll
  for (int k = 0; k < 7; ++k) p[k] = 0.0;
  const float* wb = W1 + (size_t)o0 * SP_IN + lane;
  for (int j = 0; j < 49; ++j) {
    double yv = y_s[lane + 64 * j];
    const float* wp = wb + 64 * j;
#pragma unroll
    for (int k = 0; k < 7; ++k) p[k] += (double)wp[(size_t)k * SP_IN] * yv;
  }
#pragma unroll
  for (int k = 0; k < 7; ++k) {
    double v = p[k];
#pragma unroll
    for (int d = 32; d; d >>= 1) v += __shfl_xor(v, d, 64);
    if (lane == 0) h[(size_t)b * HID + o0 + k] = v > 0.0 ? v : 0.0;
  }
}

// ---------------- K2b: GEMM2  pre = W2T^T . h (thread per output) ----------
// grid (13, 64): o = blockIdx.x*256 + t, b = blockIdx.y
__global__ __launch_bounds__(256) void k2b_gemm2(const double* __restrict__ h,
                                                 const float* __restrict__ W2T,
                                                 double* __restrict__ pre) {
  __shared__ double h_s[HID];
  const int b = blockIdx.y;
  const int o = blockIdx.x * 256 + threadIdx.x;
  for (int i = threadIdx.x; i < HID; i += 256) h_s[i] = h[(size_t)b * HID + i];
  __syncthreads();
  if (o < SP_IN) {
    double a = 0.0;
    const float* wp = W2T + o;
#pragma unroll 14
    for (int hh = 0; hh < HID; ++hh) a += (double)wp[(size_t)hh * SP_IN] * h_s[hh];
    pre[(size_t)b * SP_IN + o] = a;
  }
}

__device__ __forceinline__ unsigned int fkey(float f) {
  unsigned int u = __float_as_uint(f);
  return (u & 0x80000000u) ? ~u : (u | 0x80000000u);  // monotone total order
}

// ---------------- K2c: per-row exact top-k mask + sigmoid ------------------
__global__ __launch_bounds__(256, 1) void k2c_select(const double* __restrict__ pre,
                                                     float* __restrict__ y2m) {
  __shared__ double pre_s[SP_IN];   // 25 KB
  __shared__ unsigned int hist[256];
  __shared__ unsigned char rm_s[SP_IN];
  __shared__ int eqidx[64];
  __shared__ int eqcnt;
  __shared__ unsigned int prefix_s;
  __shared__ int rank_s;

  const int b = blockIdx.x;
  const int t = threadIdx.x;
  const int lane = t & 63, wv = t >> 6;

  for (int i = t; i < SP_IN; i += 256) pre_s[i] = pre[(size_t)b * SP_IN + i];
  if (t == 0) { eqcnt = 0; prefix_s = 0; rank_s = NREM; }
  __syncthreads();

  // Radix select (MSB-first, 4x8-bit) for the NREM-th smallest float key.
  for (int shift = 24; shift >= 0; shift -= 8) {
    hist[t] = 0;
    __syncthreads();
    const unsigned int pfx = prefix_s;
    const unsigned int pmask = (shift == 24) ? 0u : (0xFFFFFFFFu << (shift + 8));
    const int r = rank_s;
    for (int i = t; i < SP_IN; i += 256) {
      unsigned int k = fkey((float)pre_s[i]);
      if ((k & pmask) == pfx) atomicAdd(&hist[(k >> shift) & 0xFFu], 1u);
    }
    __syncthreads();
    if (wv == 0) {  // wave-parallel scan of the 256 bins
      unsigned int h0 = hist[lane * 4], h1 = hist[lane * 4 + 1],
                   h2 = hist[lane * 4 + 2], h3 = hist[lane * 4 + 3];
      unsigned int s = h0 + h1 + h2 + h3;
      unsigned int c = s;
#pragma unroll
      for (int d = 1; d < 64; d <<= 1) {
        unsigned int vv = __shfl_up(c, d, 64);
        if (lane >= d) c += vv;
      }
      unsigned int excl = c - s;
      if (excl < (unsigned)r && c >= (unsigned)r) {  // exactly one lane
        unsigned int cum = excl;
        int bsel = lane * 4;
        if (cum + h0 < (unsigned)r) { cum += h0; ++bsel;
          if (cum + h1 < (unsigned)r) { cum += h1; ++bsel;
            if (cum + h2 < (unsigned)r) { cum += h2; ++bsel; } } }
        rank_s = r - (int)cum;
        prefix_s = pfx | ((unsigned)bsel << shift);
      }
    }
    __syncthreads();
  }
  const unsigned int ustar = prefix_s;  // key of the boundary element
  const int need_eq = rank_s;           // how many key==ustar elems to remove

  for (int i = t; i < SP_IN; i += 256) {
    unsigned int k = fkey((float)pre_s[i]);
    rm_s[i] = (k < ustar) ? 1 : 0;
    if (k == ustar) { int p = atomicAdd(&eqcnt, 1); if (p < 64) eqidx[p] = i; }
  }
  __syncthreads();
  if (t == 0) {  // remove need_eq smallest by (fp64 value, index) — stable-argsort semantics
    int m = eqcnt < 64 ? eqcnt : 64;
    int ne = need_eq < m ? need_eq : m;
    unsigned long long used = 0ull;
    for (int cnt = 0; cnt < ne; ++cnt) {
      int best = -1;
      for (int j = 0; j < m; ++j) {
        if (used & (1ull << j)) continue;
        if (best < 0) { best = j; continue; }
        int ib = eqidx[best], ij = eqidx[j];
        double vb = pre_s[ib], vj = pre_s[ij];
        if (vj < vb || (vj == vb && ij < ib)) best = j;
      }
      used |= (1ull << best);
      rm_s[eqidx[best]] = 1;
    }
  }
  __syncthreads();

  for (int i = t; i < SP_IN; i += 256) {
    double sg = 1.0 / (1.0 + exp(-pre_s[i]));
    y2m[(size_t)b * SP_IN + i] = rm_s[i] ? 0.f : (float)sg;
  }
}

// ---------------- K3: broadcast masked row over 256 planes -----------------
__global__ __launch_bounds__(256) void k3_bcast(const float* __restrict__ y2m,
                                                float* __restrict__ out) {
  const int idx = blockIdx.x * 256 + threadIdx.x;  // 64 b * 64 cgroups * 784 p4
  const int p4 = idx % P4;
  const int rest = idx / P4;
  const int cg = rest & 63;
  const int b = rest >> 6;
  float4 v = ((const float4*)y2m)[b * P4 + p4];
  float4* op = (float4*)out + (size_t)b * (NPLANES * P4) + (size_t)(cg * 4) * P4 + p4;
  op[0] = v;
  op[P4] = v;
  op[2 * P4] = v;
  op[3 * P4] = v;
}

extern "C" void kernel_launch(void* const* d_in, const int* in_sizes, int n_in,
                              void* d_out, int out_size, void* d_ws, size_t ws_size,
                              hipStream_t stream) {
  (void)in_sizes; (void)n_in; (void)out_size; (void)ws_size;
  const float* x  = (const float*)d_in[0];
  const float* W1 = (const float*)d_in[1];
  const float* W2 = (const float*)d_in[2];
  float* out = (float*)d_out;

  // ws layout (bytes):
  //   [0, 2458624)                      W2T   (196*3136*4)          live k0..k2b
  //   [2458624, 8881152)                yp    (4*64*3136*8)         live k1..k2a
  //   [8881152, 8981504)                h     (64*196*8)            live k2a..k2b
  //   pre aliases yp[0.. ]  at 2458624  (64*3136*8 = 1605632)       live k2b..k2c
  //   y2m aliases yp        at 4063... = 2458624+1605632 = 4064256  live k2c..k3
  // total ws use = 8981504 B (~8.98 MB); yp is dead before pre/y2m are written.
  char* ws = (char*)d_ws;
  float*  W2T = (float*)ws;
  double* yp  = (double*)(ws + 2458624);
  double* h   = (double*)(ws + 8881152);
  double* pre = (double*)(ws + 2458624);
  float*  y2m = (float*)(ws + 4064256);

  k0_transpose<<<dim3(7, 98), dim3(32, 8), 0, stream>>>(W2, W2T);
  k1_pool<<<dim3(784), dim3(256), 0, stream>>>(x, yp);
  k2a_gemm1<<<dim3(7, NB), dim3(256), 0, stream>>>(yp, W1, h);
  k2b_gemm2<<<dim3(13, NB), dim3(256), 0, stream>>>(h, W2T, pre);
  k2c_select<<<dim3(NB), dim3(256), 0, stream>>>(pre, y2m);
  k3_bcast<<<dim3(12544), dim3(256), 0, stream>>>(y2m, out);
}